// Round 5
// baseline (1350.762 us; speedup 1.0000x reference)
//
#include <hip/hip_runtime.h>
#include <cstdint>
#include <cstddef>

#define DROPOUT_VARIANT 3  // partitionable counter (0,i), XOR of output words [verified round 2]
#define NB 256             // dest-range buckets for two-pass CSR build
#define BCAP 8192          // max staged edges per bucket (expected ~6250)

typedef short bf16x8 __attribute__((ext_vector_type(8)));
typedef float f32x4 __attribute__((ext_vector_type(4)));

// ---------------- bf16 helpers ----------------
static __device__ __forceinline__ uint32_t f2bf(float x) {
  uint32_t u = __float_as_uint(x);
  return (u + 0x7fffu + ((u >> 16) & 1u)) >> 16;  // RNE
}
static __device__ __forceinline__ uint32_t pack2(float a, float b) {
  return f2bf(a) | (f2bf(b) << 16);
}
static __device__ __forceinline__ float bf_lo(uint32_t u) { return __uint_as_float(u << 16); }
static __device__ __forceinline__ float bf_hi(uint32_t u) { return __uint_as_float(u & 0xffff0000u); }

// ---------------- Threefry-2x32-20, key (0,42) ----------------
static __device__ __forceinline__ uint32_t rotl32(uint32_t v, int d) {
  return (v << d) | (v >> (32 - d));
}

static __device__ __forceinline__ void threefry2x32(uint32_t k0, uint32_t k1,
                                                    uint32_t& x0, uint32_t& x1) {
  uint32_t k2 = k0 ^ k1 ^ 0x1BD11BDAu;
  x0 += k0; x1 += k1;
#define TF_R(r) { x0 += x1; x1 = rotl32(x1, (r)); x1 ^= x0; }
  TF_R(13) TF_R(15) TF_R(26) TF_R(6)
  x0 += k1; x1 += k2 + 1u;
  TF_R(17) TF_R(29) TF_R(16) TF_R(24)
  x0 += k2; x1 += k0 + 2u;
  TF_R(13) TF_R(15) TF_R(26) TF_R(6)
  x0 += k0; x1 += k1 + 3u;
  TF_R(17) TF_R(29) TF_R(16) TF_R(24)
  x0 += k1; x1 += k2 + 4u;
  TF_R(13) TF_R(15) TF_R(26) TF_R(6)
  x0 += k2; x1 += k0 + 5u;
#undef TF_R
}

// ---------------- graph preprocessing ----------------
__global__ void init_kernel(int* cnt, int* cursor, int* bcur, int* ovf_cnt, int n) {
  int i = blockIdx.x * blockDim.x + threadIdx.x;
  if (i < n) { cnt[i] = 0; cursor[i] = 0; }
  if (i < NB) bcur[i] = 0;
  if (i == 0) *ovf_cnt = 0;
}

// pass A: bin edges into dest-range buckets (packed src|dloc), count degrees
__global__ void bucketA_kernel(const int* __restrict__ fs, const int* __restrict__ fd,
                               uint32_t* __restrict__ stage, int* __restrict__ bcur,
                               int* __restrict__ cnt, uint2* __restrict__ ovf,
                               int* __restrict__ ovf_cnt, int bsz, int e) {
  int i = blockIdx.x * blockDim.x + threadIdx.x;
  if (i < e) {
    int s = fs[i], d = fd[i];
    atomicAdd(&cnt[d], 1);
    int b = d / bsz;                       // bucket (d < 2^17, bsz ~391)
    int pos = atomicAdd(&bcur[b], 1);
    if (pos < BCAP) {
      stage[(size_t)b * BCAP + pos] = (uint32_t)s | ((uint32_t)(d - b * bsz) << 17);
    } else {
      int op = atomicAdd(ovf_cnt, 1);
      ovf[op] = make_uint2((uint32_t)s, (uint32_t)d);
    }
  }
}

__global__ void scanA_kernel(const int* __restrict__ cnt, int* __restrict__ off,
                             int* __restrict__ bsum, int n) {
  __shared__ int s[256];
  int t = threadIdx.x;
  int i = blockIdx.x * 256 + t;
  int v = (i < n) ? cnt[i] : 0;
  s[t] = v;
  __syncthreads();
  for (int d = 1; d < 256; d <<= 1) {
    int add = (t >= d) ? s[t - d] : 0;
    __syncthreads();
    s[t] += add;
    __syncthreads();
  }
  if (i < n) off[i] = s[t] - v;  // exclusive
  if (t == 255) bsum[blockIdx.x] = s[255];
}

__global__ void scanB_kernel(const int* __restrict__ bsum, int* __restrict__ boff,
                             int nb, int* __restrict__ off, int n) {
  __shared__ int s[512];
  int t = threadIdx.x;
  int v = (t < nb) ? bsum[t] : 0;
  s[t] = v;
  __syncthreads();
  for (int d = 1; d < 512; d <<= 1) {
    int add = (t >= d) ? s[t - d] : 0;
    __syncthreads();
    s[t] += add;
    __syncthreads();
  }
  if (t < nb) boff[t] = s[t] - v;
  if (t == nb - 1) off[n] = s[t];  // total = E
}

__global__ void scanC_kernel(int* __restrict__ off, const int* __restrict__ boff,
                             const int* __restrict__ cnt, float* __restrict__ dis, int n) {
  int i = blockIdx.x * 256 + threadIdx.x;
  if (i < n) {
    off[i] += boff[blockIdx.x];
    dis[i] = 1.0f / sqrtf((float)(cnt[i] + 1));  // deg includes self-loop
  }
}

// pass B: fine scatter within a bucket's ~50KB csr window (L2-resident)
__global__ void bucketB_kernel(const uint32_t* __restrict__ stage,
                               const int* __restrict__ bcur,
                               const uint2* __restrict__ ovf,
                               const int* __restrict__ ovf_cnt,
                               const int* __restrict__ off, int* __restrict__ cursor,
                               const float* __restrict__ dis,
                               uint2* __restrict__ csr, int bsz) {
  int b = blockIdx.x;
  if (b < NB) {
    int cntb = min(bcur[b], BCAP);
    int dbase = b * bsz;
    const uint32_t* src = stage + (size_t)b * BCAP;
    for (int i = threadIdx.x; i < cntb; i += blockDim.x) {
      uint32_t v = src[i];
      int s = (int)(v & 0x1ffffu);
      int d = dbase + (int)(v >> 17);
      int pos = atomicAdd(&cursor[d], 1);
      csr[off[d] + pos] = make_uint2((uint32_t)s, __float_as_uint(dis[s] * dis[d]));
    }
  } else {
    int cntb = *ovf_cnt;
    for (int i = threadIdx.x; i < cntb; i += blockDim.x) {
      uint2 sd = ovf[i];
      int s = (int)sd.x, d = (int)sd.y;
      int pos = atomicAdd(&cursor[d], 1);
      csr[off[d] + pos] = make_uint2((uint32_t)s, __float_as_uint(dis[s] * dis[d]));
    }
  }
}

// h = query[batch] * x : write fp32 h (residual path) + bf16 hb (GEMM input)
__global__ void h0_kernel(const float* __restrict__ x, const float* __restrict__ query,
                          const int* __restrict__ batch, float* __restrict__ h,
                          uint32_t* __restrict__ hb, int n) {
  int i = blockIdx.x * blockDim.x + threadIdx.x;  // one bf16x2 word (2 cols)
  int total = n * 64;
  if (i < total) {
    int node = i >> 6;
    int w = i & 63;
    int b = batch[node];
    float2 xv = ((const float2*)x)[i];
    float2 qv = ((const float2*)query)[b * 64 + w];
    float2 r = make_float2(xv.x * qv.x, xv.y * qv.y);
    ((float2*)h)[i] = r;
    hb[i] = pack2(r.x, r.y);
  }
}

// ---------------- MFMA GEMM: C[nrows,BN] = A_bf16[nrows,128] @ W_f32[128,BN] ----------------
// W split into bf16 hi+lo -> two MFMAs per k-step give ~fp32-grade accuracy.
// Block: 256 rows x BN cols, 4 waves x 64 rows. A-frags loaded directly from global.
// OUT_BF16==0 (classifier): fuses +bias and JAX-threefry dropout into the store.
template<int BN, int OUT_BF16>
__global__ __launch_bounds__(256)
void mfma_gemm_kernel(const uint32_t* __restrict__ Abf,   // bf16x2 words, row stride 64
                      const float* __restrict__ Wm,       // fp32 [128][BN] row-major
                      const float* __restrict__ bias,     // nullptr or [BN]
                      void* __restrict__ Cout, int nrows) {
  constexpr int CT = BN / 16;                 // col tiles per wave
  __shared__ short Wt[2][BN][136];            // [hi/lo][col][k] bf16 bits
  const int tid = threadIdx.x;

  // stage W: fp32 row-major [k][col] -> transposed bf16 hi/lo [col][k]
  for (int q = tid; q < (128 * BN) / 4; q += 256) {
    int el = q * 4;
    int k = el / BN;
    int col = el % BN;                        // 4 consecutive cols, same k
    float4 w4 = *(const float4*)(Wm + el);
    float wv[4] = {w4.x, w4.y, w4.z, w4.w};
#pragma unroll
    for (int j = 0; j < 4; ++j) {
      uint32_t hi = f2bf(wv[j]);
      float hif = __uint_as_float(hi << 16);
      uint32_t lo = f2bf(wv[j] - hif);
      Wt[0][col + j][k] = (short)hi;
      Wt[1][col + j][k] = (short)lo;
    }
  }
  __syncthreads();

  const int wave = tid >> 6;
  const int lane = tid & 63;
  const int lrow = lane & 15;                 // A-row / B-col within tile
  const int lk = lane >> 4;                   // k-group (0..3)
  const int rowbase = blockIdx.x * 256 + wave * 64;
  const uint16_t* Au = (const uint16_t*)Abf;

  f32x4 acc[4][CT];
#pragma unroll
  for (int rt = 0; rt < 4; ++rt)
#pragma unroll
    for (int ct = 0; ct < CT; ++ct) acc[rt][ct] = (f32x4){0.f, 0.f, 0.f, 0.f};

#pragma unroll
  for (int s = 0; s < 4; ++s) {               // K-steps of 32
    bf16x8 a[4];
#pragma unroll
    for (int rt = 0; rt < 4; ++rt) {
      int gr = rowbase + rt * 16 + lrow;
      int gra = (gr < nrows) ? gr : 0;        // clamp; stores are guarded
      a[rt] = *reinterpret_cast<const bf16x8*>(Au + (size_t)gra * 128 + s * 32 + lk * 8);
    }
#pragma unroll
    for (int ct = 0; ct < CT; ++ct) {
      bf16x8 bhi = *reinterpret_cast<const bf16x8*>(&Wt[0][ct * 16 + lrow][s * 32 + lk * 8]);
      bf16x8 blo = *reinterpret_cast<const bf16x8*>(&Wt[1][ct * 16 + lrow][s * 32 + lk * 8]);
#pragma unroll
      for (int rt = 0; rt < 4; ++rt)
        acc[rt][ct] = __builtin_amdgcn_mfma_f32_16x16x32_bf16(a[rt], bhi, acc[rt][ct], 0, 0, 0);
#pragma unroll
      for (int rt = 0; rt < 4; ++rt)
        acc[rt][ct] = __builtin_amdgcn_mfma_f32_16x16x32_bf16(a[rt], blo, acc[rt][ct], 0, 0, 0);
    }
  }

  // store: C/D mapping col=lane&15, row=(lane>>4)*4+reg
#pragma unroll
  for (int rt = 0; rt < 4; ++rt)
#pragma unroll
    for (int ct = 0; ct < CT; ++ct)
#pragma unroll
      for (int r = 0; r < 4; ++r) {
        int gr = rowbase + rt * 16 + lk * 4 + r;
        if (gr >= nrows) continue;
        int col = ct * 16 + lrow;
        float v = acc[rt][ct][r];
        if constexpr (OUT_BF16) {
          ((uint16_t*)Cout)[(size_t)gr * BN + col] = (uint16_t)f2bf(v);
        } else {
          v += bias[col];
          // fused JAX dropout (variant 3): counter (0, gr*BN+col), xor words
          uint32_t x0 = 0u, x1 = (uint32_t)gr * (uint32_t)BN + (uint32_t)col;
          threefry2x32(0u, 42u, x0, x1);
          uint32_t bits = x0 ^ x1;
          float u = __uint_as_float((bits >> 9) | 0x3F800000u) - 1.0f;
          ((float*)Cout)[(size_t)gr * BN + col] = (u < 0.8f) ? (v / 0.8f) : 0.0f;
        }
      }
}

// ---------------- aggregation: one wave64 per node, bf16 rows, 8-way unroll ----------------
__global__ __launch_bounds__(256)
void agg_kernel(const uint32_t* __restrict__ hwb, float* __restrict__ h,
                uint32_t* __restrict__ hb, const float* __restrict__ bias,
                const int* __restrict__ off, const uint2* __restrict__ csr,
                const float* __restrict__ dis, int relu, int n) {
  int wid = (blockIdx.x * blockDim.x + threadIdx.x) >> 6;
  int lane = threadIdx.x & 63;
  if (wid >= n) return;
  int v = wid;
  float dv = dis[v];
  float sw = dv * dv;
  uint32_t hvw = hwb[(size_t)v * 64 + lane];
  float2* hr = (float2*)(h + (size_t)v * 128);
  float2 res = hr[lane];
  float2 bb = ((const float2*)bias)[lane];
  float accx = fmaf(sw, bf_lo(hvw), bb.x + res.x);
  float accy = fmaf(sw, bf_hi(hvw), bb.y + res.y);
  int s0 = off[v], s1 = off[v + 1];
  int i = s0;
  for (; i + 7 < s1; i += 8) {
    uint2 c[8];
    uint32_t r[8];
#pragma unroll
    for (int j = 0; j < 8; ++j) c[j] = csr[i + j];
#pragma unroll
    for (int j = 0; j < 8; ++j) r[j] = hwb[(size_t)c[j].x * 64 + lane];
#pragma unroll
    for (int j = 0; j < 8; ++j) {
      float w = __uint_as_float(c[j].y);
      accx = fmaf(w, bf_lo(r[j]), accx);
      accy = fmaf(w, bf_hi(r[j]), accy);
    }
  }
  for (; i + 3 < s1; i += 4) {
    uint2 c[4];
    uint32_t r[4];
#pragma unroll
    for (int j = 0; j < 4; ++j) c[j] = csr[i + j];
#pragma unroll
    for (int j = 0; j < 4; ++j) r[j] = hwb[(size_t)c[j].x * 64 + lane];
#pragma unroll
    for (int j = 0; j < 4; ++j) {
      float w = __uint_as_float(c[j].y);
      accx = fmaf(w, bf_lo(r[j]), accx);
      accy = fmaf(w, bf_hi(r[j]), accy);
    }
  }
  for (; i < s1; ++i) {
    uint2 c = csr[i];
    uint32_t r = hwb[(size_t)c.x * 64 + lane];
    float w = __uint_as_float(c.y);
    accx = fmaf(w, bf_lo(r), accx);
    accy = fmaf(w, bf_hi(r), accy);
  }
  if (relu) { accx = fmaxf(accx, 0.f); accy = fmaxf(accy, 0.f); }
  hr[lane] = make_float2(accx, accy);
  hb[(size_t)v * 64 + lane] = pack2(accx, accy);
}

// ---------------- launch ----------------
extern "C" void kernel_launch(void* const* d_in, const int* in_sizes, int n_in,
                              void* d_out, int out_size, void* d_ws, size_t ws_size,
                              hipStream_t stream) {
  const float* x     = (const float*)d_in[0];
  const float* query = (const float*)d_in[1];
  const int*   batch = (const int*)d_in[2];
  const int*   eidx  = (const int*)d_in[3];
  const float* W[4]  = {(const float*)d_in[4], (const float*)d_in[6],
                        (const float*)d_in[8], (const float*)d_in[10]};
  const float* bv[4] = {(const float*)d_in[5], (const float*)d_in[7],
                        (const float*)d_in[9], (const float*)d_in[11]};
  const float* Wc = (const float*)d_in[12];
  const float* bc = (const float*)d_in[13];
  float* out = (float*)d_out;

  const int n = in_sizes[2];       // 100000  (packing assumes n < 2^17)
  const int e = in_sizes[3] / 2;   // 1600000
  const int* fs = eidx;            // edge_index[0] = sources
  const int* fd = eidx + e;        // edge_index[1] = targets (aggregation index)
  const int bsz = (n + NB - 1) / NB;  // 391 (< 512, fits 9-bit local offset... uses 15 bits)

  char* p = (char*)d_ws;
  auto carve = [&](size_t bytes) -> void* {
    void* r = (void*)p;
    p += (bytes + 255) & ~(size_t)255;
    return r;
  };
  const int nscan = (n + 255) / 256;           // 391 (<= 512 for scanB)
  int*      cnt     = (int*)carve((size_t)n * 4);
  int*      cursor  = (int*)carve((size_t)n * 4);
  int*      off     = (int*)carve((size_t)(n + 1) * 4);
  int*      bsum    = (int*)carve((size_t)nscan * 4);
  int*      boff    = (int*)carve((size_t)nscan * 4);
  int*      bcur    = (int*)carve((size_t)NB * 4);
  int*      ovf_cnt = (int*)carve(4);
  float*    dis     = (float*)carve((size_t)n * 4);
  uint32_t* stage   = (uint32_t*)carve((size_t)NB * BCAP * 4);  // 8.4 MB
  uint2*    ovf     = (uint2*)carve((size_t)65536 * 8);
  uint2*    csr     = (uint2*)carve((size_t)e * 8);             // interleaved {src, w}
  float*    h       = (float*)carve((size_t)n * 128 * 4);       // fp32 residual
  uint32_t* hb      = (uint32_t*)carve((size_t)n * 64 * 4);     // bf16 h (GEMM input)
  uint32_t* hwb     = (uint32_t*)carve((size_t)n * 64 * 4);     // bf16 h@W (gather src)

  const int eb = (e + 255) / 256;

  init_kernel<<<nscan, 256, 0, stream>>>(cnt, cursor, bcur, ovf_cnt, n);
  bucketA_kernel<<<eb, 256, 0, stream>>>(fs, fd, stage, bcur, cnt, ovf, ovf_cnt, bsz, e);
  scanA_kernel<<<nscan, 256, 0, stream>>>(cnt, off, bsum, n);
  scanB_kernel<<<1, 512, 0, stream>>>(bsum, boff, nscan, off, n);
  scanC_kernel<<<nscan, 256, 0, stream>>>(off, boff, cnt, dis, n);
  bucketB_kernel<<<NB + 1, 256, 0, stream>>>(stage, bcur, ovf, ovf_cnt, off, cursor,
                                             dis, csr, bsz);
  h0_kernel<<<(n * 64 + 255) / 256, 256, 0, stream>>>(x, query, batch, h, hb, n);

  const int gblk = (n + 255) / 256;
  for (int l = 0; l < 4; ++l) {
    mfma_gemm_kernel<128, 1><<<gblk, 256, 0, stream>>>(hb, W[l], nullptr, hwb, n);
    agg_kernel<<<(n + 3) / 4, 256, 0, stream>>>(hwb, h, hb, bv[l], off, csr,
                                                dis, (l < 3) ? 1 : 0, n);
  }
  mfma_gemm_kernel<64, 0><<<gblk, 256, 0, stream>>>(hb, Wc, bc, out, n);
}

// Round 6
// 609.767 us; speedup vs baseline: 2.2152x; 2.2152x over previous
//
#include <hip/hip_runtime.h>
#include <cstdint>
#include <cstddef>

// CSR-build lesson (round 5): 256 hot atomic counters serialize (~787us);
// 100K distributed cursors are fine. This version: rank precomputed in the
// count pass, fill is an atomic-free pure scatter.

typedef short bf16x8 __attribute__((ext_vector_type(8)));
typedef float f32x4 __attribute__((ext_vector_type(4)));

// ---------------- bf16 helpers ----------------
static __device__ __forceinline__ uint32_t f2bf(float x) {
  uint32_t u = __float_as_uint(x);
  return (u + 0x7fffu + ((u >> 16) & 1u)) >> 16;  // RNE
}
static __device__ __forceinline__ uint32_t pack2(float a, float b) {
  return f2bf(a) | (f2bf(b) << 16);
}
static __device__ __forceinline__ float bf_lo(uint32_t u) { return __uint_as_float(u << 16); }
static __device__ __forceinline__ float bf_hi(uint32_t u) { return __uint_as_float(u & 0xffff0000u); }

// ---------------- Threefry-2x32-20, key (0,42) ----------------
static __device__ __forceinline__ uint32_t rotl32(uint32_t v, int d) {
  return (v << d) | (v >> (32 - d));
}

static __device__ __forceinline__ void threefry2x32(uint32_t k0, uint32_t k1,
                                                    uint32_t& x0, uint32_t& x1) {
  uint32_t k2 = k0 ^ k1 ^ 0x1BD11BDAu;
  x0 += k0; x1 += k1;
#define TF_R(r) { x0 += x1; x1 = rotl32(x1, (r)); x1 ^= x0; }
  TF_R(13) TF_R(15) TF_R(26) TF_R(6)
  x0 += k1; x1 += k2 + 1u;
  TF_R(17) TF_R(29) TF_R(16) TF_R(24)
  x0 += k2; x1 += k0 + 2u;
  TF_R(13) TF_R(15) TF_R(26) TF_R(6)
  x0 += k0; x1 += k1 + 3u;
  TF_R(17) TF_R(29) TF_R(16) TF_R(24)
  x0 += k1; x1 += k2 + 4u;
  TF_R(13) TF_R(15) TF_R(26) TF_R(6)
  x0 += k2; x1 += k0 + 5u;
#undef TF_R
}

// ---------------- graph preprocessing ----------------
__global__ void init_kernel(int* cnt, int n) {
  int i = blockIdx.x * blockDim.x + threadIdx.x;
  if (i < n) cnt[i] = 0;
}

// count degrees AND assign each edge its within-destination rank
__global__ void count_rank_kernel(const int* __restrict__ fd, int* __restrict__ cnt,
                                  int* __restrict__ rank, int e) {
  int i = blockIdx.x * blockDim.x + threadIdx.x;
  if (i < e) rank[i] = atomicAdd(&cnt[fd[i]], 1);
}

__global__ void scanA_kernel(const int* __restrict__ cnt, int* __restrict__ off,
                             int* __restrict__ bsum, int n) {
  __shared__ int s[256];
  int t = threadIdx.x;
  int i = blockIdx.x * 256 + t;
  int v = (i < n) ? cnt[i] : 0;
  s[t] = v;
  __syncthreads();
  for (int d = 1; d < 256; d <<= 1) {
    int add = (t >= d) ? s[t - d] : 0;
    __syncthreads();
    s[t] += add;
    __syncthreads();
  }
  if (i < n) off[i] = s[t] - v;  // exclusive
  if (t == 255) bsum[blockIdx.x] = s[255];
}

__global__ void scanB_kernel(const int* __restrict__ bsum, int* __restrict__ boff,
                             int nb, int* __restrict__ off, int n) {
  __shared__ int s[512];
  int t = threadIdx.x;
  int v = (t < nb) ? bsum[t] : 0;
  s[t] = v;
  __syncthreads();
  for (int d = 1; d < 512; d <<= 1) {
    int add = (t >= d) ? s[t - d] : 0;
    __syncthreads();
    s[t] += add;
    __syncthreads();
  }
  if (t < nb) boff[t] = s[t] - v;
  if (t == nb - 1) off[n] = s[t];  // total = E
}

__global__ void scanC_kernel(int* __restrict__ off, const int* __restrict__ boff,
                             const int* __restrict__ cnt, float* __restrict__ dis, int n) {
  int i = blockIdx.x * 256 + threadIdx.x;
  if (i < n) {
    off[i] += boff[blockIdx.x];
    dis[i] = 1.0f / sqrtf((float)(cnt[i] + 1));  // deg includes self-loop
  }
}

// atomic-free scatter: slot = off[d] + rank[i]
__global__ void fill_kernel(const int* __restrict__ fs, const int* __restrict__ fd,
                            const int* __restrict__ rank, const int* __restrict__ off,
                            const float* __restrict__ dis,
                            uint2* __restrict__ csr, int e) {
  int i = blockIdx.x * blockDim.x + threadIdx.x;
  if (i < e) {
    int s = fs[i], d = fd[i];
    csr[off[d] + rank[i]] = make_uint2((uint32_t)s, __float_as_uint(dis[s] * dis[d]));
  }
}

// h = query[batch] * x : write fp32 h (residual path) + bf16 hb (GEMM input)
__global__ void h0_kernel(const float* __restrict__ x, const float* __restrict__ query,
                          const int* __restrict__ batch, float* __restrict__ h,
                          uint32_t* __restrict__ hb, int n) {
  int i = blockIdx.x * blockDim.x + threadIdx.x;  // one bf16x2 word (2 cols)
  int total = n * 64;
  if (i < total) {
    int node = i >> 6;
    int w = i & 63;
    int b = batch[node];
    float2 xv = ((const float2*)x)[i];
    float2 qv = ((const float2*)query)[b * 64 + w];
    float2 r = make_float2(xv.x * qv.x, xv.y * qv.y);
    ((float2*)h)[i] = r;
    hb[i] = pack2(r.x, r.y);
  }
}

// ---------------- MFMA GEMM: C[nrows,BN] = A_bf16[nrows,128] @ W_f32[128,BN] ----------------
// W split into bf16 hi+lo -> two MFMAs per k-step give ~fp32-grade accuracy.
// Block: 256 rows x BN cols, 4 waves x 64 rows. A-frags loaded directly from global.
// OUT_BF16==0 (classifier): fuses +bias and JAX-threefry dropout into the store.
template<int BN, int OUT_BF16>
__global__ __launch_bounds__(256)
void mfma_gemm_kernel(const uint32_t* __restrict__ Abf,   // bf16x2 words, row stride 64
                      const float* __restrict__ Wm,       // fp32 [128][BN] row-major
                      const float* __restrict__ bias,     // nullptr or [BN]
                      void* __restrict__ Cout, int nrows) {
  constexpr int CT = BN / 16;                 // col tiles per wave
  __shared__ short Wt[2][BN][136];            // [hi/lo][col][k] bf16 bits
  const int tid = threadIdx.x;

  // stage W: fp32 row-major [k][col] -> transposed bf16 hi/lo [col][k]
  for (int q = tid; q < (128 * BN) / 4; q += 256) {
    int el = q * 4;
    int k = el / BN;
    int col = el % BN;                        // 4 consecutive cols, same k
    float4 w4 = *(const float4*)(Wm + el);
    float wv[4] = {w4.x, w4.y, w4.z, w4.w};
#pragma unroll
    for (int j = 0; j < 4; ++j) {
      uint32_t hi = f2bf(wv[j]);
      float hif = __uint_as_float(hi << 16);
      uint32_t lo = f2bf(wv[j] - hif);
      Wt[0][col + j][k] = (short)hi;
      Wt[1][col + j][k] = (short)lo;
    }
  }
  __syncthreads();

  const int wave = tid >> 6;
  const int lane = tid & 63;
  const int lrow = lane & 15;                 // A-row / B-col within tile
  const int lk = lane >> 4;                   // k-group (0..3)
  const int rowbase = blockIdx.x * 256 + wave * 64;
  const uint16_t* Au = (const uint16_t*)Abf;

  f32x4 acc[4][CT];
#pragma unroll
  for (int rt = 0; rt < 4; ++rt)
#pragma unroll
    for (int ct = 0; ct < CT; ++ct) acc[rt][ct] = (f32x4){0.f, 0.f, 0.f, 0.f};

#pragma unroll
  for (int s = 0; s < 4; ++s) {               // K-steps of 32
    bf16x8 a[4];
#pragma unroll
    for (int rt = 0; rt < 4; ++rt) {
      int gr = rowbase + rt * 16 + lrow;
      int gra = (gr < nrows) ? gr : 0;        // clamp; stores are guarded
      a[rt] = *reinterpret_cast<const bf16x8*>(Au + (size_t)gra * 128 + s * 32 + lk * 8);
    }
#pragma unroll
    for (int ct = 0; ct < CT; ++ct) {
      bf16x8 bhi = *reinterpret_cast<const bf16x8*>(&Wt[0][ct * 16 + lrow][s * 32 + lk * 8]);
      bf16x8 blo = *reinterpret_cast<const bf16x8*>(&Wt[1][ct * 16 + lrow][s * 32 + lk * 8]);
#pragma unroll
      for (int rt = 0; rt < 4; ++rt)
        acc[rt][ct] = __builtin_amdgcn_mfma_f32_16x16x32_bf16(a[rt], bhi, acc[rt][ct], 0, 0, 0);
#pragma unroll
      for (int rt = 0; rt < 4; ++rt)
        acc[rt][ct] = __builtin_amdgcn_mfma_f32_16x16x32_bf16(a[rt], blo, acc[rt][ct], 0, 0, 0);
    }
  }

  // store: C/D mapping col=lane&15, row=(lane>>4)*4+reg
#pragma unroll
  for (int rt = 0; rt < 4; ++rt)
#pragma unroll
    for (int ct = 0; ct < CT; ++ct)
#pragma unroll
      for (int r = 0; r < 4; ++r) {
        int gr = rowbase + rt * 16 + lk * 4 + r;
        if (gr >= nrows) continue;
        int col = ct * 16 + lrow;
        float v = acc[rt][ct][r];
        if constexpr (OUT_BF16) {
          ((uint16_t*)Cout)[(size_t)gr * BN + col] = (uint16_t)f2bf(v);
        } else {
          v += bias[col];
          // fused JAX dropout (variant 3): counter (0, gr*BN+col), xor words
          uint32_t x0 = 0u, x1 = (uint32_t)gr * (uint32_t)BN + (uint32_t)col;
          threefry2x32(0u, 42u, x0, x1);
          uint32_t bits = x0 ^ x1;
          float u = __uint_as_float((bits >> 9) | 0x3F800000u) - 1.0f;
          ((float*)Cout)[(size_t)gr * BN + col] = (u < 0.8f) ? (v / 0.8f) : 0.0f;
        }
      }
}

// ---------------- aggregation: one wave64 per node, bf16 rows, 8-way unroll ----------------
__global__ __launch_bounds__(256)
void agg_kernel(const uint32_t* __restrict__ hwb, float* __restrict__ h,
                uint32_t* __restrict__ hb, const float* __restrict__ bias,
                const int* __restrict__ off, const uint2* __restrict__ csr,
                const float* __restrict__ dis, int relu, int n) {
  int wid = (blockIdx.x * blockDim.x + threadIdx.x) >> 6;
  int lane = threadIdx.x & 63;
  if (wid >= n) return;
  int v = wid;
  float dv = dis[v];
  float sw = dv * dv;
  uint32_t hvw = hwb[(size_t)v * 64 + lane];
  float2* hr = (float2*)(h + (size_t)v * 128);
  float2 res = hr[lane];
  float2 bb = ((const float2*)bias)[lane];
  float accx = fmaf(sw, bf_lo(hvw), bb.x + res.x);
  float accy = fmaf(sw, bf_hi(hvw), bb.y + res.y);
  int s0 = off[v], s1 = off[v + 1];
  int i = s0;
  for (; i + 7 < s1; i += 8) {
    uint2 c[8];
    uint32_t r[8];
#pragma unroll
    for (int j = 0; j < 8; ++j) c[j] = csr[i + j];
#pragma unroll
    for (int j = 0; j < 8; ++j) r[j] = hwb[(size_t)c[j].x * 64 + lane];
#pragma unroll
    for (int j = 0; j < 8; ++j) {
      float w = __uint_as_float(c[j].y);
      accx = fmaf(w, bf_lo(r[j]), accx);
      accy = fmaf(w, bf_hi(r[j]), accy);
    }
  }
  for (; i + 3 < s1; i += 4) {
    uint2 c[4];
    uint32_t r[4];
#pragma unroll
    for (int j = 0; j < 4; ++j) c[j] = csr[i + j];
#pragma unroll
    for (int j = 0; j < 4; ++j) r[j] = hwb[(size_t)c[j].x * 64 + lane];
#pragma unroll
    for (int j = 0; j < 4; ++j) {
      float w = __uint_as_float(c[j].y);
      accx = fmaf(w, bf_lo(r[j]), accx);
      accy = fmaf(w, bf_hi(r[j]), accy);
    }
  }
  for (; i < s1; ++i) {
    uint2 c = csr[i];
    uint32_t r = hwb[(size_t)c.x * 64 + lane];
    float w = __uint_as_float(c.y);
    accx = fmaf(w, bf_lo(r), accx);
    accy = fmaf(w, bf_hi(r), accy);
  }
  if (relu) { accx = fmaxf(accx, 0.f); accy = fmaxf(accy, 0.f); }
  hr[lane] = make_float2(accx, accy);
  hb[(size_t)v * 64 + lane] = pack2(accx, accy);
}

// ---------------- launch ----------------
extern "C" void kernel_launch(void* const* d_in, const int* in_sizes, int n_in,
                              void* d_out, int out_size, void* d_ws, size_t ws_size,
                              hipStream_t stream) {
  const float* x     = (const float*)d_in[0];
  const float* query = (const float*)d_in[1];
  const int*   batch = (const int*)d_in[2];
  const int*   eidx  = (const int*)d_in[3];
  const float* W[4]  = {(const float*)d_in[4], (const float*)d_in[6],
                        (const float*)d_in[8], (const float*)d_in[10]};
  const float* bv[4] = {(const float*)d_in[5], (const float*)d_in[7],
                        (const float*)d_in[9], (const float*)d_in[11]};
  const float* Wc = (const float*)d_in[12];
  const float* bc = (const float*)d_in[13];
  float* out = (float*)d_out;

  const int n = in_sizes[2];       // 100000
  const int e = in_sizes[3] / 2;   // 1600000
  const int* fs = eidx;            // edge_index[0] = sources
  const int* fd = eidx + e;        // edge_index[1] = targets (aggregation index)

  char* p = (char*)d_ws;
  auto carve = [&](size_t bytes) -> void* {
    void* r = (void*)p;
    p += (bytes + 255) & ~(size_t)255;
    return r;
  };
  const int nscan = (n + 255) / 256;           // 391 (<= 512 for scanB)
  int*      cnt     = (int*)carve((size_t)n * 4);
  int*      off     = (int*)carve((size_t)(n + 1) * 4);
  int*      bsum    = (int*)carve((size_t)nscan * 4);
  int*      boff    = (int*)carve((size_t)nscan * 4);
  int*      rank    = (int*)carve((size_t)e * 4);
  float*    dis     = (float*)carve((size_t)n * 4);
  uint2*    csr     = (uint2*)carve((size_t)e * 8);             // interleaved {src, w}
  float*    h       = (float*)carve((size_t)n * 128 * 4);       // fp32 residual
  uint32_t* hb      = (uint32_t*)carve((size_t)n * 64 * 4);     // bf16 h (GEMM input)
  uint32_t* hwb     = (uint32_t*)carve((size_t)n * 64 * 4);     // bf16 h@W (gather src)

  const int eb = (e + 255) / 256;

  init_kernel<<<nscan, 256, 0, stream>>>(cnt, n);
  count_rank_kernel<<<eb, 256, 0, stream>>>(fd, cnt, rank, e);
  scanA_kernel<<<nscan, 256, 0, stream>>>(cnt, off, bsum, n);
  scanB_kernel<<<1, 512, 0, stream>>>(bsum, boff, nscan, off, n);
  scanC_kernel<<<nscan, 256, 0, stream>>>(off, boff, cnt, dis, n);
  fill_kernel<<<eb, 256, 0, stream>>>(fs, fd, rank, off, dis, csr, e);
  h0_kernel<<<(n * 64 + 255) / 256, 256, 0, stream>>>(x, query, batch, h, hb, n);

  const int gblk = (n + 255) / 256;
  for (int l = 0; l < 4; ++l) {
    mfma_gemm_kernel<128, 1><<<gblk, 256, 0, stream>>>(hb, W[l], nullptr, hwb, n);
    agg_kernel<<<(n + 3) / 4, 256, 0, stream>>>(hwb, h, hb, bv[l], off, csr,
                                                dis, (l < 3) ? 1 : 0, n);
  }
  mfma_gemm_kernel<64, 0><<<gblk, 256, 0, stream>>>(hb, Wc, bc, out, n);
}

// Round 7
// 570.623 us; speedup vs baseline: 2.3672x; 1.0686x over previous
//
#include <hip/hip_runtime.h>
#include <cstdint>
#include <cstddef>

// CSR-build lesson (round 5): hot atomic counters serialize; distributed
// per-node cursors are fine. Rank precomputed in count pass; fill is pure scatter.
// Round 7: residual kept in bf16 (hb) — fp32 h array deleted; agg updates hb in place.

typedef short bf16x8 __attribute__((ext_vector_type(8)));
typedef float f32x4 __attribute__((ext_vector_type(4)));

// ---------------- bf16 helpers ----------------
static __device__ __forceinline__ uint32_t f2bf(float x) {
  uint32_t u = __float_as_uint(x);
  return (u + 0x7fffu + ((u >> 16) & 1u)) >> 16;  // RNE
}
static __device__ __forceinline__ uint32_t pack2(float a, float b) {
  return f2bf(a) | (f2bf(b) << 16);
}
static __device__ __forceinline__ float bf_lo(uint32_t u) { return __uint_as_float(u << 16); }
static __device__ __forceinline__ float bf_hi(uint32_t u) { return __uint_as_float(u & 0xffff0000u); }

// ---------------- Threefry-2x32-20, key (0,42) ----------------
static __device__ __forceinline__ uint32_t rotl32(uint32_t v, int d) {
  return (v << d) | (v >> (32 - d));
}

static __device__ __forceinline__ void threefry2x32(uint32_t k0, uint32_t k1,
                                                    uint32_t& x0, uint32_t& x1) {
  uint32_t k2 = k0 ^ k1 ^ 0x1BD11BDAu;
  x0 += k0; x1 += k1;
#define TF_R(r) { x0 += x1; x1 = rotl32(x1, (r)); x1 ^= x0; }
  TF_R(13) TF_R(15) TF_R(26) TF_R(6)
  x0 += k1; x1 += k2 + 1u;
  TF_R(17) TF_R(29) TF_R(16) TF_R(24)
  x0 += k2; x1 += k0 + 2u;
  TF_R(13) TF_R(15) TF_R(26) TF_R(6)
  x0 += k0; x1 += k1 + 3u;
  TF_R(17) TF_R(29) TF_R(16) TF_R(24)
  x0 += k1; x1 += k2 + 4u;
  TF_R(13) TF_R(15) TF_R(26) TF_R(6)
  x0 += k2; x1 += k0 + 5u;
#undef TF_R
}

// ---------------- graph preprocessing ----------------
__global__ void init_kernel(int* cnt, int n) {
  int i = blockIdx.x * blockDim.x + threadIdx.x;
  if (i < n) cnt[i] = 0;
}

// count degrees AND assign each edge its within-destination rank
__global__ void count_rank_kernel(const int* __restrict__ fd, int* __restrict__ cnt,
                                  int* __restrict__ rank, int e) {
  int i = blockIdx.x * blockDim.x + threadIdx.x;
  if (i < e) rank[i] = atomicAdd(&cnt[fd[i]], 1);
}

__global__ void scanA_kernel(const int* __restrict__ cnt, int* __restrict__ off,
                             int* __restrict__ bsum, int n) {
  __shared__ int s[256];
  int t = threadIdx.x;
  int i = blockIdx.x * 256 + t;
  int v = (i < n) ? cnt[i] : 0;
  s[t] = v;
  __syncthreads();
  for (int d = 1; d < 256; d <<= 1) {
    int add = (t >= d) ? s[t - d] : 0;
    __syncthreads();
    s[t] += add;
    __syncthreads();
  }
  if (i < n) off[i] = s[t] - v;  // exclusive
  if (t == 255) bsum[blockIdx.x] = s[255];
}

__global__ void scanB_kernel(const int* __restrict__ bsum, int* __restrict__ boff,
                             int nb, int* __restrict__ off, int n) {
  __shared__ int s[512];
  int t = threadIdx.x;
  int v = (t < nb) ? bsum[t] : 0;
  s[t] = v;
  __syncthreads();
  for (int d = 1; d < 512; d <<= 1) {
    int add = (t >= d) ? s[t - d] : 0;
    __syncthreads();
    s[t] += add;
    __syncthreads();
  }
  if (t < nb) boff[t] = s[t] - v;
  if (t == nb - 1) off[n] = s[t];  // total = E
}

__global__ void scanC_kernel(int* __restrict__ off, const int* __restrict__ boff,
                             const int* __restrict__ cnt, float* __restrict__ dis, int n) {
  int i = blockIdx.x * 256 + threadIdx.x;
  if (i < n) {
    off[i] += boff[blockIdx.x];
    dis[i] = 1.0f / sqrtf((float)(cnt[i] + 1));  // deg includes self-loop
  }
}

// atomic-free scatter: slot = off[d] + rank[i]
__global__ void fill_kernel(const int* __restrict__ fs, const int* __restrict__ fd,
                            const int* __restrict__ rank, const int* __restrict__ off,
                            const float* __restrict__ dis,
                            uint2* __restrict__ csr, int e) {
  int i = blockIdx.x * blockDim.x + threadIdx.x;
  if (i < e) {
    int s = fs[i], d = fd[i];
    csr[off[d] + rank[i]] = make_uint2((uint32_t)s, __float_as_uint(dis[s] * dis[d]));
  }
}

// h0 = query[batch] * x -> bf16 hb only (residual lives in bf16 from here on)
__global__ void h0_kernel(const float* __restrict__ x, const float* __restrict__ query,
                          const int* __restrict__ batch, uint32_t* __restrict__ hb, int n) {
  int i = blockIdx.x * blockDim.x + threadIdx.x;  // one bf16x2 word (2 cols)
  int total = n * 64;
  if (i < total) {
    int node = i >> 6;
    int w = i & 63;
    int b = batch[node];
    float2 xv = ((const float2*)x)[i];
    float2 qv = ((const float2*)query)[b * 64 + w];
    hb[i] = pack2(xv.x * qv.x, xv.y * qv.y);
  }
}

// ---------------- MFMA GEMM: C[nrows,BN] = A_bf16[nrows,128] @ W_f32[128,BN] ----------------
// W split into bf16 hi+lo -> two MFMAs per k-step give ~fp32-grade accuracy.
// Block: 256 rows x BN cols, 4 waves x 64 rows. A-frags loaded directly from global.
// OUT_BF16==0 (classifier): fuses +bias and JAX-threefry dropout into the store.
template<int BN, int OUT_BF16>
__global__ __launch_bounds__(256)
void mfma_gemm_kernel(const uint32_t* __restrict__ Abf,   // bf16x2 words, row stride 64
                      const float* __restrict__ Wm,       // fp32 [128][BN] row-major
                      const float* __restrict__ bias,     // nullptr or [BN]
                      void* __restrict__ Cout, int nrows) {
  constexpr int CT = BN / 16;                 // col tiles per wave
  __shared__ short Wt[2][BN][136];            // [hi/lo][col][k] bf16 bits
  const int tid = threadIdx.x;

  // stage W: fp32 row-major [k][col] -> transposed bf16 hi/lo [col][k]
  for (int q = tid; q < (128 * BN) / 4; q += 256) {
    int el = q * 4;
    int k = el / BN;
    int col = el % BN;                        // 4 consecutive cols, same k
    float4 w4 = *(const float4*)(Wm + el);
    float wv[4] = {w4.x, w4.y, w4.z, w4.w};
#pragma unroll
    for (int j = 0; j < 4; ++j) {
      uint32_t hi = f2bf(wv[j]);
      float hif = __uint_as_float(hi << 16);
      uint32_t lo = f2bf(wv[j] - hif);
      Wt[0][col + j][k] = (short)hi;
      Wt[1][col + j][k] = (short)lo;
    }
  }
  __syncthreads();

  const int wave = tid >> 6;
  const int lane = tid & 63;
  const int lrow = lane & 15;                 // A-row / B-col within tile
  const int lk = lane >> 4;                   // k-group (0..3)
  const int rowbase = blockIdx.x * 256 + wave * 64;
  const uint16_t* Au = (const uint16_t*)Abf;

  f32x4 acc[4][CT];
#pragma unroll
  for (int rt = 0; rt < 4; ++rt)
#pragma unroll
    for (int ct = 0; ct < CT; ++ct) acc[rt][ct] = (f32x4){0.f, 0.f, 0.f, 0.f};

#pragma unroll
  for (int s = 0; s < 4; ++s) {               // K-steps of 32
    bf16x8 a[4];
#pragma unroll
    for (int rt = 0; rt < 4; ++rt) {
      int gr = rowbase + rt * 16 + lrow;
      int gra = (gr < nrows) ? gr : 0;        // clamp; stores are guarded
      a[rt] = *reinterpret_cast<const bf16x8*>(Au + (size_t)gra * 128 + s * 32 + lk * 8);
    }
#pragma unroll
    for (int ct = 0; ct < CT; ++ct) {
      bf16x8 bhi = *reinterpret_cast<const bf16x8*>(&Wt[0][ct * 16 + lrow][s * 32 + lk * 8]);
      bf16x8 blo = *reinterpret_cast<const bf16x8*>(&Wt[1][ct * 16 + lrow][s * 32 + lk * 8]);
#pragma unroll
      for (int rt = 0; rt < 4; ++rt)
        acc[rt][ct] = __builtin_amdgcn_mfma_f32_16x16x32_bf16(a[rt], bhi, acc[rt][ct], 0, 0, 0);
#pragma unroll
      for (int rt = 0; rt < 4; ++rt)
        acc[rt][ct] = __builtin_amdgcn_mfma_f32_16x16x32_bf16(a[rt], blo, acc[rt][ct], 0, 0, 0);
    }
  }

  // store: C/D mapping col=lane&15, row=(lane>>4)*4+reg
#pragma unroll
  for (int rt = 0; rt < 4; ++rt)
#pragma unroll
    for (int ct = 0; ct < CT; ++ct)
#pragma unroll
      for (int r = 0; r < 4; ++r) {
        int gr = rowbase + rt * 16 + lk * 4 + r;
        if (gr >= nrows) continue;
        int col = ct * 16 + lrow;
        float v = acc[rt][ct][r];
        if constexpr (OUT_BF16) {
          ((uint16_t*)Cout)[(size_t)gr * BN + col] = (uint16_t)f2bf(v);
        } else {
          v += bias[col];
          // fused JAX dropout (variant 3): counter (0, gr*BN+col), xor words
          uint32_t x0 = 0u, x1 = (uint32_t)gr * (uint32_t)BN + (uint32_t)col;
          threefry2x32(0u, 42u, x0, x1);
          uint32_t bits = x0 ^ x1;
          float u = __uint_as_float((bits >> 9) | 0x3F800000u) - 1.0f;
          ((float*)Cout)[(size_t)gr * BN + col] = (u < 0.8f) ? (v / 0.8f) : 0.0f;
        }
      }
}

// ---------------- aggregation: one wave64 per node, bf16 rows, 8-way unroll ----------------
// hb[v] := maybe_relu( bias + hb[v](res,bf16) + dis^2*hwb[v] + sum_edges w*hwb[src] )
// in-place hb update is safe: agg never reads other nodes' hb.
__global__ __launch_bounds__(256)
void agg_kernel(const uint32_t* __restrict__ hwb, uint32_t* __restrict__ hb,
                const float* __restrict__ bias,
                const int* __restrict__ off, const uint2* __restrict__ csr,
                const float* __restrict__ dis, int relu, int n) {
  int wid = (blockIdx.x * blockDim.x + threadIdx.x) >> 6;
  int lane = threadIdx.x & 63;
  if (wid >= n) return;
  int v = wid;
  float dv = dis[v];
  float sw = dv * dv;
  uint32_t hvw = hwb[(size_t)v * 64 + lane];
  uint32_t resw = hb[(size_t)v * 64 + lane];
  float2 bb = ((const float2*)bias)[lane];
  float accx = fmaf(sw, bf_lo(hvw), bb.x + bf_lo(resw));
  float accy = fmaf(sw, bf_hi(hvw), bb.y + bf_hi(resw));
  int s0 = off[v], s1 = off[v + 1];
  int i = s0;
  for (; i + 7 < s1; i += 8) {
    uint2 c[8];
    uint32_t r[8];
#pragma unroll
    for (int j = 0; j < 8; ++j) c[j] = csr[i + j];
#pragma unroll
    for (int j = 0; j < 8; ++j) r[j] = hwb[(size_t)c[j].x * 64 + lane];
#pragma unroll
    for (int j = 0; j < 8; ++j) {
      float w = __uint_as_float(c[j].y);
      accx = fmaf(w, bf_lo(r[j]), accx);
      accy = fmaf(w, bf_hi(r[j]), accy);
    }
  }
  for (; i + 3 < s1; i += 4) {
    uint2 c[4];
    uint32_t r[4];
#pragma unroll
    for (int j = 0; j < 4; ++j) c[j] = csr[i + j];
#pragma unroll
    for (int j = 0; j < 4; ++j) r[j] = hwb[(size_t)c[j].x * 64 + lane];
#pragma unroll
    for (int j = 0; j < 4; ++j) {
      float w = __uint_as_float(c[j].y);
      accx = fmaf(w, bf_lo(r[j]), accx);
      accy = fmaf(w, bf_hi(r[j]), accy);
    }
  }
  for (; i < s1; ++i) {
    uint2 c = csr[i];
    uint32_t r = hwb[(size_t)c.x * 64 + lane];
    float w = __uint_as_float(c.y);
    accx = fmaf(w, bf_lo(r), accx);
    accy = fmaf(w, bf_hi(r), accy);
  }
  if (relu) { accx = fmaxf(accx, 0.f); accy = fmaxf(accy, 0.f); }
  hb[(size_t)v * 64 + lane] = pack2(accx, accy);
}

// ---------------- launch ----------------
extern "C" void kernel_launch(void* const* d_in, const int* in_sizes, int n_in,
                              void* d_out, int out_size, void* d_ws, size_t ws_size,
                              hipStream_t stream) {
  const float* x     = (const float*)d_in[0];
  const float* query = (const float*)d_in[1];
  const int*   batch = (const int*)d_in[2];
  const int*   eidx  = (const int*)d_in[3];
  const float* W[4]  = {(const float*)d_in[4], (const float*)d_in[6],
                        (const float*)d_in[8], (const float*)d_in[10]};
  const float* bv[4] = {(const float*)d_in[5], (const float*)d_in[7],
                        (const float*)d_in[9], (const float*)d_in[11]};
  const float* Wc = (const float*)d_in[12];
  const float* bc = (const float*)d_in[13];
  float* out = (float*)d_out;

  const int n = in_sizes[2];       // 100000
  const int e = in_sizes[3] / 2;   // 1600000
  const int* fs = eidx;            // edge_index[0] = sources
  const int* fd = eidx + e;        // edge_index[1] = targets (aggregation index)

  char* p = (char*)d_ws;
  auto carve = [&](size_t bytes) -> void* {
    void* r = (void*)p;
    p += (bytes + 255) & ~(size_t)255;
    return r;
  };
  const int nscan = (n + 255) / 256;           // 391 (<= 512 for scanB)
  int*      cnt     = (int*)carve((size_t)n * 4);
  int*      off     = (int*)carve((size_t)(n + 1) * 4);
  int*      bsum    = (int*)carve((size_t)nscan * 4);
  int*      boff    = (int*)carve((size_t)nscan * 4);
  int*      rank    = (int*)carve((size_t)e * 4);
  float*    dis     = (float*)carve((size_t)n * 4);
  uint2*    csr     = (uint2*)carve((size_t)e * 8);             // interleaved {src, w}
  uint32_t* hb      = (uint32_t*)carve((size_t)n * 64 * 4);     // bf16 h (residual + GEMM input)
  uint32_t* hwb     = (uint32_t*)carve((size_t)n * 64 * 4);     // bf16 h@W (gather src)

  const int eb = (e + 255) / 256;

  init_kernel<<<nscan, 256, 0, stream>>>(cnt, n);
  count_rank_kernel<<<eb, 256, 0, stream>>>(fd, cnt, rank, e);
  scanA_kernel<<<nscan, 256, 0, stream>>>(cnt, off, bsum, n);
  scanB_kernel<<<1, 512, 0, stream>>>(bsum, boff, nscan, off, n);
  scanC_kernel<<<nscan, 256, 0, stream>>>(off, boff, cnt, dis, n);
  fill_kernel<<<eb, 256, 0, stream>>>(fs, fd, rank, off, dis, csr, e);
  h0_kernel<<<(n * 64 + 255) / 256, 256, 0, stream>>>(x, query, batch, hb, n);

  const int gblk = (n + 255) / 256;
  for (int l = 0; l < 4; ++l) {
    mfma_gemm_kernel<128, 1><<<gblk, 256, 0, stream>>>(hb, W[l], nullptr, hwb, n);
    agg_kernel<<<(n + 3) / 4, 256, 0, stream>>>(hwb, hb, bv[l], off, csr,
                                                dis, (l < 3) ? 1 : 0, n);
  }
  mfma_gemm_kernel<64, 0><<<gblk, 256, 0, stream>>>(hb, Wc, bc, out, n);
}